// Round 6
// baseline (157.382 us; speedup 1.0000x reference)
//
#include <hip/hip_runtime.h>
#include <math.h>

// Problem constants
#define QDIM 512     // 2^9 state dim
#define DD   128     // K*C_IN = input dim of quadratic form
#define LIN  4096
#define LOUT 4089    // (4096 - 7 - 1)/1 + 1
#define NC   16      // C_IN
#define NB   16      // batch

// ---------------------------------------------------------------------------
// Scratch lives in device globals (NOT d_ws): we never verified ws_size is
// >= 589 KB, and OOB ws writes can clobber adjacent allocations (e.g. the
// instantiated graph's device state) -> layout-dependent post-timing
// divergence. .bss globals are private to the .so and capture-safe.
// Every element is rewritten each call before being read (ry l=0 synthesizes
// the identity without reading g_B), so no cross-call state dependence.
// ---------------------------------------------------------------------------
__device__ float g_B[QDIM * DD];
__device__ float g_C[QDIM * DD];
__device__ float g_Q[DD * DD];

// ---------------------------------------------------------------------------
// Precompute: A = (E*R3*E*R2*E*R1)[:, :128], then Q = A^T S A  (S=diag(+-1))
// Buffers are 512x128 row-major [state i][col j].  Ping-pong: sel=l&1 picks
// g_B (sel=0) or g_C (sel=1) as the "current" buffer.
// ---------------------------------------------------------------------------

// Apply RY layer l to each column of the current buffer (in place).
// first!=0: treat buffer as identity (skip load, synthesize e_j).
__global__ void ry_kernel(const float* __restrict__ theta, int l, int first, int sel) {
  float* B = sel ? g_C : g_B;
  __shared__ float col[QDIM];
  int j = blockIdx.x;
  int p = threadIdx.x;              // 0..255
  if (first) {
    col[p]       = (p == j) ? 1.0f : 0.0f;
    col[p + 256] = 0.0f;            // j < 128 < 256
  } else {
    col[p]       = B[p * DD + j];
    col[p + 256] = B[(p + 256) * DD + j];
  }
  __syncthreads();
  #pragma unroll
  for (int q = 0; q < 9; ++q) {
    float half = theta[l * 9 + q] * 0.5f;
    float c = cosf(half), s = sinf(half);
    int right = QDIM >> (q + 1);
    int a = p >> (8 - q);
    int r = p & (right - 1);
    int i0 = (a * 2) * right + r;
    int i1 = i0 + right;
    // pairs (i0,i1) partition [0,512) across threads -> no intra-step hazard
    float v0 = col[i0], v1 = col[i1];
    col[i0] = c * v0 - s * v1;
    col[i1] = s * v0 + c * v1;
    __syncthreads();
  }
  B[p * DD + j]         = col[p];
  B[(p + 256) * DD + j] = col[p + 256];
}

// dst = E (512x512) * src (512x128); src = sel ? g_C : g_B, dst = the other.
// One block per row i; 256 thr = 128 j x 2 K-halves.
__global__ __launch_bounds__(256) void mm_kernel(const float* __restrict__ E, int sel) {
  const float* B = sel ? g_C : g_B;
  float* C       = sel ? g_B : g_C;
  __shared__ float erow[QDIM];
  __shared__ float part[DD];
  int i = blockIdx.x;
  int tid = threadIdx.x;
  int j = tid & 127, h = tid >> 7;
  for (int m = tid; m < QDIM; m += 256) erow[m] = E[i * QDIM + m];
  __syncthreads();
  float a0 = 0.f, a1 = 0.f, a2 = 0.f, a3 = 0.f;
  int m0 = h * 256;
  #pragma unroll 8
  for (int m = m0; m < m0 + 256; m += 4) {
    a0 = fmaf(erow[m + 0], B[(m + 0) * DD + j], a0);
    a1 = fmaf(erow[m + 1], B[(m + 1) * DD + j], a1);
    a2 = fmaf(erow[m + 2], B[(m + 2) * DD + j], a2);
    a3 = fmaf(erow[m + 3], B[(m + 3) * DD + j], a3);
  }
  float sum = (a0 + a1) + (a2 + a3);
  if (h == 1) part[j] = sum;
  __syncthreads();
  if (h == 0) C[i * DD + j] = sum + part[j];
}

// g_Q[j1][j2] = sum_i sgn(i) A[i][j1] A[i][j2];  A = g_C (result after l=2).
__global__ __launch_bounds__(256) void formq_kernel() {
  const float* A = g_C;
  __shared__ float colA[QDIM];
  __shared__ float part[DD];
  int j1 = blockIdx.x;
  int tid = threadIdx.x;
  int j2 = tid & 127, h = tid >> 7;
  for (int i = tid; i < QDIM; i += 256) {
    float sgn = (i < 256) ? 1.0f : -1.0f;
    colA[i] = sgn * A[i * DD + j1];
  }
  __syncthreads();
  float a0 = 0.f, a1 = 0.f, a2 = 0.f, a3 = 0.f;
  int i0 = h * 256;
  #pragma unroll 8
  for (int i = i0; i < i0 + 256; i += 4) {
    a0 = fmaf(colA[i + 0], A[(i + 0) * DD + j2], a0);
    a1 = fmaf(colA[i + 1], A[(i + 1) * DD + j2], a1);
    a2 = fmaf(colA[i + 2], A[(i + 2) * DD + j2], a2);
    a3 = fmaf(colA[i + 3], A[(i + 3) * DD + j2], a3);
  }
  float sum = (a0 + a1) + (a2 + a3);
  if (h == 1) part[j2] = sum;
  __syncthreads();
  if (h == 0) g_Q[j1 * DD + j2] = sum + part[j2];
}

// ---------------------------------------------------------------------------
// Main pass: out[b,t] = v^T Q v / (v^T v + 1e-12),  v[c*8+k] = x[b,c,t+k]
// Block = 64 t's x 4 i-chunk waves. Wave s owns u[i], i in [32s,32s+32).
// Q chunk address is wave-uniform (readfirstlane) -> scalar-load friendly.
// ---------------------------------------------------------------------------
__global__ __launch_bounds__(256, 4) void quad_kernel(const float* __restrict__ x,
                                                      float* __restrict__ out) {
  __shared__ float xs[NC][72];      // 71 used (64 t + 7 halo)
  __shared__ float pdot[4][64];
  __shared__ float pnrm[4][64];
  int b = blockIdx.x;
  int t0 = blockIdx.y * 64;
  int tid = threadIdx.x;
  int l = tid & 63;                 // t within tile (lane)
  int s = tid >> 6;                 // i-chunk == wave id
  const float* xb = x + (size_t)b * NC * LIN;

  for (int idx = tid; idx < NC * 71; idx += 256) {
    int c = idx / 71, o = idx % 71;
    int g = t0 + o;
    xs[c][o] = (g < LIN) ? xb[c * LIN + g] : 0.0f;
  }
  __syncthreads();

  int su = __builtin_amdgcn_readfirstlane(s);
  const float* qbase = g_Q + su * 32;

  float u[32];
  #pragma unroll
  for (int i = 0; i < 32; ++i) u[i] = 0.0f;

  #pragma unroll 2
  for (int j = 0; j < 128; ++j) {
    float vj = xs[j >> 3][l + (j & 7)];
    const float4* qr = (const float4*)(qbase + (size_t)j * DD);
    #pragma unroll
    for (int i4 = 0; i4 < 8; ++i4) {
      float4 q4 = qr[i4];
      u[i4 * 4 + 0] = fmaf(q4.x, vj, u[i4 * 4 + 0]);
      u[i4 * 4 + 1] = fmaf(q4.y, vj, u[i4 * 4 + 1]);
      u[i4 * 4 + 2] = fmaf(q4.z, vj, u[i4 * 4 + 2]);
      u[i4 * 4 + 3] = fmaf(q4.w, vj, u[i4 * 4 + 3]);
    }
  }

  float dot = 0.0f, nrm = 0.0f;
  #pragma unroll
  for (int i = 0; i < 32; ++i) {
    int ii = su * 32 + i;
    float vi = xs[ii >> 3][l + (ii & 7)];
    dot = fmaf(vi, u[i], dot);
    nrm = fmaf(vi, vi, nrm);
  }
  pdot[s][l] = dot;
  pnrm[s][l] = nrm;
  __syncthreads();
  if (s == 0) {
    float d = pdot[0][l] + pdot[1][l] + pdot[2][l] + pdot[3][l];
    float n = pnrm[0][l] + pnrm[1][l] + pnrm[2][l] + pnrm[3][l];
    int t = t0 + l;
    if (t < LOUT) out[(size_t)b * LOUT + t] = d / (n + 1e-12f);
  }
}

// ---------------------------------------------------------------------------

extern "C" void kernel_launch(void* const* d_in, const int* in_sizes, int n_in,
                              void* d_out, int out_size, void* d_ws, size_t ws_size,
                              hipStream_t stream) {
  const float* x     = (const float*)d_in[0];   // (16,16,4096) f32
  const float* E     = (const float*)d_in[1];   // (512,512)    f32
  const float* theta = (const float*)d_in[2];   // (3,9)        f32
  float* out = (float*)d_out;                   // (16,1,1,4089) f32
  (void)d_ws; (void)ws_size;                    // scratch is in device globals

  for (int l = 0; l < 3; ++l) {
    ry_kernel<<<DD, 256, 0, stream>>>(theta, l, l == 0 ? 1 : 0, l & 1);
    mm_kernel<<<QDIM, 256, 0, stream>>>(E, l & 1);
  }
  // after l=2 (sel=0), result A lives in g_C
  formq_kernel<<<DD, 256, 0, stream>>>();

  quad_kernel<<<dim3(NB, 64), 256, 0, stream>>>(x, out);
}

// Round 7
// 75.982 us; speedup vs baseline: 2.0713x; 2.0713x over previous
//
#include <hip/hip_runtime.h>
#include <math.h>

// Problem constants
#define QDIM 512     // 2^9 state dim
#define DD   128     // K*C_IN = input dim of quadratic form
#define LIN  4096
#define LOUT 4089    // (4096 - 7 - 1)/1 + 1
#define NC   16      // C_IN
#define NB   16      // batch

// Scratch in device globals (NOT d_ws) — R5 lesson: unchecked ws usage can
// clobber adjacent allocations (post-timing divergence). Every element is
// rewritten each call before being read -> no cross-call state.
__device__ float g_B[QDIM * DD];
__device__ float g_C[QDIM * DD];
__device__ float g_Q[DD * DD];

// ---------------------------------------------------------------------------
// Precompute, fused form. A = (E*R3*E*R2*E*R1)[:, :128].
// Row i of E*R*W equals (R^T e_i)^T W, where R^T applies the transposed
// butterflies ( [[c,s],[-s,c]] ) in REVERSE qubit order (q=8..0).
// Layer 1 with W = I_{512x128}: row i of W1 is just (R1^T e_i)[0:128].
// ---------------------------------------------------------------------------

__device__ __forceinline__ void butterfly_T(float* col, const float* theta,
                                            int l, int p) {
  // col[512] in LDS; 256 threads p handle 256 disjoint pairs per qubit step.
  #pragma unroll
  for (int qq = 0; qq < 9; ++qq) {
    int q = 8 - qq;                    // reverse order for transpose
    float half = theta[l * 9 + q] * 0.5f;
    float c = cosf(half), s = sinf(half);
    int right = QDIM >> (q + 1);       // 2^(8-q)
    int a = p >> (8 - q);
    int r = p & (right - 1);
    int i0 = (a * 2) * right + r;
    int i1 = i0 + right;
    float v0 = col[i0], v1 = col[i1];
    col[i0] = c * v0 + s * v1;         // transposed 2x2
    col[i1] = c * v1 - s * v0;
    __syncthreads();
  }
}

// W1[i][j] = (R1^T e_i)[j], j<128.  One block per row i.
__global__ __launch_bounds__(256) void w1_kernel(const float* __restrict__ E,
                                                 const float* __restrict__ theta) {
  __shared__ float erow[QDIM];
  int i = blockIdx.x;
  int p = threadIdx.x;
  erow[p]       = E[i * QDIM + p];
  erow[p + 256] = E[i * QDIM + p + 256];
  __syncthreads();
  butterfly_T(erow, theta, 0, p);
  if (p < DD) g_B[i * DD + p] = erow[p];
}

// dst[i][:] = (R_l^T e_i)^T * src.  src/dst ping-pong on sel.
// 256 thr = 128 j x 2 K-halves.
__global__ __launch_bounds__(256) void mm_fused_kernel(const float* __restrict__ E,
                                                       const float* __restrict__ theta,
                                                       int l, int sel) {
  const float* W = sel ? g_C : g_B;
  float* D       = sel ? g_B : g_C;
  __shared__ float erow[QDIM];
  __shared__ float part[DD];
  int i = blockIdx.x;
  int tid = threadIdx.x;
  erow[tid]       = E[i * QDIM + tid];
  erow[tid + 256] = E[i * QDIM + tid + 256];
  __syncthreads();
  butterfly_T(erow, theta, l, tid);

  int j = tid & 127, h = tid >> 7;
  float a0 = 0.f, a1 = 0.f, a2 = 0.f, a3 = 0.f;
  int m0 = h * 256;
  #pragma unroll 8
  for (int m = m0; m < m0 + 256; m += 4) {
    a0 = fmaf(erow[m + 0], W[(m + 0) * DD + j], a0);
    a1 = fmaf(erow[m + 1], W[(m + 1) * DD + j], a1);
    a2 = fmaf(erow[m + 2], W[(m + 2) * DD + j], a2);
    a3 = fmaf(erow[m + 3], W[(m + 3) * DD + j], a3);
  }
  float sum = (a0 + a1) + (a2 + a3);
  if (h == 1) part[j] = sum;
  __syncthreads();
  if (h == 0) D[i * DD + j] = sum + part[j];
}

// g_Q[j1][j2] = sum_i sgn(i) A[i][j1] A[i][j2];  A lives in g_B
// (chain: w1 -> g_B, mm l=1 -> g_C, mm l=2 -> g_B).
__global__ __launch_bounds__(256) void formq_kernel() {
  const float* A = g_B;
  __shared__ float colA[QDIM];
  __shared__ float part[DD];
  int j1 = blockIdx.x;
  int tid = threadIdx.x;
  int j2 = tid & 127, h = tid >> 7;
  for (int i = tid; i < QDIM; i += 256) {
    float sgn = (i < 256) ? 1.0f : -1.0f;
    colA[i] = sgn * A[i * DD + j1];
  }
  __syncthreads();
  float a0 = 0.f, a1 = 0.f, a2 = 0.f, a3 = 0.f;
  int i0 = h * 256;
  #pragma unroll 8
  for (int i = i0; i < i0 + 256; i += 4) {
    a0 = fmaf(colA[i + 0], A[(i + 0) * DD + j2], a0);
    a1 = fmaf(colA[i + 1], A[(i + 1) * DD + j2], a1);
    a2 = fmaf(colA[i + 2], A[(i + 2) * DD + j2], a2);
    a3 = fmaf(colA[i + 3], A[(i + 3) * DD + j2], a3);
  }
  float sum = (a0 + a1) + (a2 + a3);
  if (h == 1) part[j2] = sum;
  __syncthreads();
  if (h == 0) g_Q[j1 * DD + j2] = sum + part[j2];
}

// ---------------------------------------------------------------------------
// Main pass: out[b,t] = v^T Q v / (v^T v + 1e-12),  v[c*8+k] = x[b,c,t+k]
// Block = 64 t's x 4 i-chunk waves; wave s owns u[32] for i in [32s,32s+32).
// ---------------------------------------------------------------------------
__global__ __launch_bounds__(256, 4) void quad_kernel(const float* __restrict__ x,
                                                      float* __restrict__ out) {
  __shared__ float xs[NC][72];      // 71 used (64 t + 7 halo)
  __shared__ float pdot[4][64];
  __shared__ float pnrm[4][64];
  int b = blockIdx.x;
  int t0 = blockIdx.y * 64;
  int tid = threadIdx.x;
  int l = tid & 63;
  int s = tid >> 6;
  const float* xb = x + (size_t)b * NC * LIN;

  for (int idx = tid; idx < NC * 71; idx += 256) {
    int c = idx / 71, o = idx % 71;
    int g = t0 + o;
    xs[c][o] = (g < LIN) ? xb[c * LIN + g] : 0.0f;
  }
  __syncthreads();

  int su = __builtin_amdgcn_readfirstlane(s);
  const float* qbase = g_Q + su * 32;

  float u[32];
  #pragma unroll
  for (int i = 0; i < 32; ++i) u[i] = 0.0f;

  #pragma unroll 2
  for (int j = 0; j < 128; ++j) {
    float vj = xs[j >> 3][l + (j & 7)];
    const float4* qr = (const float4*)(qbase + (size_t)j * DD);
    #pragma unroll
    for (int i4 = 0; i4 < 8; ++i4) {
      float4 q4 = qr[i4];
      u[i4 * 4 + 0] = fmaf(q4.x, vj, u[i4 * 4 + 0]);
      u[i4 * 4 + 1] = fmaf(q4.y, vj, u[i4 * 4 + 1]);
      u[i4 * 4 + 2] = fmaf(q4.z, vj, u[i4 * 4 + 2]);
      u[i4 * 4 + 3] = fmaf(q4.w, vj, u[i4 * 4 + 3]);
    }
  }

  float dot = 0.0f, nrm = 0.0f;
  #pragma unroll
  for (int i = 0; i < 32; ++i) {
    int ii = su * 32 + i;
    float vi = xs[ii >> 3][l + (ii & 7)];
    dot = fmaf(vi, u[i], dot);
    nrm = fmaf(vi, vi, nrm);
  }
  pdot[s][l] = dot;
  pnrm[s][l] = nrm;
  __syncthreads();
  if (s == 0) {
    float d = pdot[0][l] + pdot[1][l] + pdot[2][l] + pdot[3][l];
    float n = pnrm[0][l] + pnrm[1][l] + pnrm[2][l] + pnrm[3][l];
    int t = t0 + l;
    if (t < LOUT) out[(size_t)b * LOUT + t] = d / (n + 1e-12f);
  }
}

// ---------------------------------------------------------------------------

extern "C" void kernel_launch(void* const* d_in, const int* in_sizes, int n_in,
                              void* d_out, int out_size, void* d_ws, size_t ws_size,
                              hipStream_t stream) {
  const float* x     = (const float*)d_in[0];   // (16,16,4096) f32
  const float* E     = (const float*)d_in[1];   // (512,512)    f32
  const float* theta = (const float*)d_in[2];   // (3,9)        f32
  float* out = (float*)d_out;                   // (16,1,1,4089) f32
  (void)d_ws; (void)ws_size;

  w1_kernel<<<QDIM, 256, 0, stream>>>(E, theta);            // -> g_B
  mm_fused_kernel<<<QDIM, 256, 0, stream>>>(E, theta, 1, 0); // g_B -> g_C
  mm_fused_kernel<<<QDIM, 256, 0, stream>>>(E, theta, 2, 1); // g_C -> g_B
  formq_kernel<<<DD, 256, 0, stream>>>();                    // g_B -> g_Q
  quad_kernel<<<dim3(NB, 64), 256, 0, stream>>>(x, out);
}